// Round 17
// baseline (455.815 us; speedup 1.0000x reference)
//
#include <hip/hip_runtime.h>

typedef short short8 __attribute__((ext_vector_type(8)));
typedef float f32x4 __attribute__((ext_vector_type(4)));
typedef unsigned short u16;

#define TOK_N 8192      // B*S
#define DMODEL 1024
#define NEXP 16
#define FEXP 512
#define NROUTED 14
#define KSEL 6
#define MAXTILES 400    // sum ceil(cnt_e/128) <= 49152/128 + 16

__device__ __forceinline__ u16 f2bf(float f) {
  unsigned u = __float_as_uint(f);
  u += 0x7fff + ((u >> 16) & 1);   // round-to-nearest-even
  return (u16)(u >> 16);
}

typedef const __attribute__((address_space(1))) unsigned int* gas_p;
typedef __attribute__((address_space(3))) unsigned int* las_p;
// wave-uniform LDS base + lane*16; per-lane global src (16B each)
__device__ __forceinline__ void gload_lds16(const void* g, void* l) {
  __builtin_amdgcn_global_load_lds((gas_p)g, (las_p)l, 16, 0, 0);
}

// ---------------- cast f32 -> bf16 (token stream) ----------------
__global__ void cast_bf16_k(const float* __restrict__ in, u16* __restrict__ out, int n8) {
  int i = blockIdx.x * blockDim.x + threadIdx.x;
  if (i >= n8) return;
  const float4* p = (const float4*)(in + (size_t)i * 8);
  float4 a = p[0], b = p[1];
  short8 v;
  v[0] = (short)f2bf(a.x); v[1] = (short)f2bf(a.y); v[2] = (short)f2bf(a.z); v[3] = (short)f2bf(a.w);
  v[4] = (short)f2bf(b.x); v[5] = (short)f2bf(b.y); v[6] = (short)f2bf(b.z); v[7] = (short)f2bf(b.w);
  *(short8*)(out + (size_t)i * 8) = v;
}

// ---------------- final cast: bf16 accum buffer -> f32 out ----------------
__global__ void cast_out_k(const u16* __restrict__ in, float* __restrict__ o) {
  int i = blockIdx.x * 256 + threadIdx.x;   // 4096 blocks x 256 thr x 8 elems
  short8 v = *(const short8*)(in + (size_t)i * 8);
  float4 a, b;
  a.x = __uint_as_float(((unsigned)(u16)v[0]) << 16);
  a.y = __uint_as_float(((unsigned)(u16)v[1]) << 16);
  a.z = __uint_as_float(((unsigned)(u16)v[2]) << 16);
  a.w = __uint_as_float(((unsigned)(u16)v[3]) << 16);
  b.x = __uint_as_float(((unsigned)(u16)v[4]) << 16);
  b.y = __uint_as_float(((unsigned)(u16)v[5]) << 16);
  b.z = __uint_as_float(((unsigned)(u16)v[6]) << 16);
  b.w = __uint_as_float(((unsigned)(u16)v[7]) << 16);
  float4* op = (float4*)(o + (size_t)i * 8);
  op[0] = a; op[1] = b;
}

// ------------- transpose + cast: in [e][R][C] f32 -> out [e][C][R] bf16 -------------
__global__ void transpose_cast_k(const float* __restrict__ in, u16* __restrict__ out, int R, int C) {
  __shared__ u16 tile[32][33];
  int e = blockIdx.z;
  int c0 = blockIdx.x * 32, r0 = blockIdx.y * 32;
  int x = threadIdx.x, y = threadIdx.y;   // block (32,8)
  const float* ip = in + ((size_t)e * R + r0) * C + c0;
  #pragma unroll
  for (int i = 0; i < 4; i++)
    tile[y + 8 * i][x] = f2bf(ip[(size_t)(y + 8 * i) * C + x]);
  __syncthreads();
  u16* op = out + ((size_t)e * C + c0) * R + r0;
  #pragma unroll
  for (int i = 0; i < 4; i++)
    op[(size_t)(y + 8 * i) * R + x] = tile[x][y + 8 * i];
}

// ---------------- routing pass A: logits, sigmoid, stable top-4 (NO global atomics) ----
__global__ void routing_k(const float* __restrict__ selin, const float* __restrict__ esel,
                          const float* __restrict__ bias, float* __restrict__ out_sel,
                          unsigned* __restrict__ sel_pack, float* __restrict__ aff6) {
  int tok = blockIdx.x;
  int t = threadIdx.x;
  int e = t & 15, chunk = t >> 4;          // 16 experts x 16 chunks of 64 elems
  const float4* r4 = (const float4*)(selin + (size_t)tok * DMODEL + chunk * 64);
  const float4* w4 = (const float4*)(esel + (size_t)e * DMODEL + chunk * 64);
  float p = 0.f;
  #pragma unroll
  for (int i = 0; i < 16; i++) {
    float4 a = r4[i], b = w4[i];
    p += a.x * b.x + a.y * b.y + a.z * b.z + a.w * b.w;
  }
  __shared__ float part[16][17];
  __shared__ float aff[16];
  __shared__ float lbias[NROUTED];
  if (t < NROUTED) lbias[t] = bias[t];
  part[chunk][e] = p;
  __syncthreads();
  if (t < 16) {
    float s = 0.f;
    #pragma unroll
    for (int c = 0; c < 16; c++) s += part[c][t];
    aff[t] = 1.f / (1.f + expf(-s));
  }
  __syncthreads();
  if (t == 0) {
    unsigned pack = 0;
    unsigned taken = 0;
    #pragma unroll
    for (int k = 0; k < 4; k++) {
      float best = -3.4e38f; int bi = 0;
      for (int q = 0; q < NROUTED; q++) {
        if (taken & (1u << q)) continue;
        float v = aff[q] + lbias[q];
        if (v > best) { best = v; bi = q; }   // strict > => lowest index wins ties (top_k stable)
      }
      taken |= 1u << bi;
      pack |= (unsigned)bi << (4 * k);
      out_sel[(size_t)tok * KSEL + k] = (float)bi;
      aff6[(size_t)tok * KSEL + k] = aff[bi];
    }
    pack |= 14u << 16; pack |= 15u << 20;
    out_sel[(size_t)tok * KSEL + 4] = 14.f;
    out_sel[(size_t)tok * KSEL + 5] = 15.f;
    aff6[(size_t)tok * KSEL + 4] = aff[14];
    aff6[(size_t)tok * KSEL + 5] = aff[15];
    sel_pack[tok] = pack;
  }
}

// ---------------- routing pass B: hierarchical scatter into per-expert lists ----------
// counts padded: expert e lives at counts[e*16] (64B stride -> no cache-line sharing)
__global__ void scatter_k(const unsigned* __restrict__ sel_pack, const float* __restrict__ aff6,
                          int* __restrict__ counts, int* __restrict__ tokk,
                          float* __restrict__ affl) {
  __shared__ int lcnt[16], lbase[16], lcur[16];
  int t = threadIdx.x;
  int tok = blockIdx.x * 256 + t;
  if (t < 16) lcnt[t] = 0;
  __syncthreads();
  unsigned pack = sel_pack[tok];
  int eid[KSEL];
  #pragma unroll
  for (int k = 0; k < KSEL; k++) {
    eid[k] = (pack >> (4 * k)) & 15;
    atomicAdd(&lcnt[eid[k]], 1);
  }
  __syncthreads();
  if (t < 16) {
    lbase[t] = atomicAdd(&counts[t * 16], lcnt[t]);
    lcur[t] = 0;
  }
  __syncthreads();
  #pragma unroll
  for (int k = 0; k < KSEL; k++) {
    int e = eid[k];
    int slot = lbase[e] + atomicAdd(&lcur[e], 1);
    tokk[e * TOK_N + slot] = tok * 8 + k;
    affl[e * TOK_N + slot] = aff6[(size_t)tok * KSEL + k];
  }
}

// ---------------- build compact tile list + per-expert prefix base, parallel ----------
// tiles[slot] = e | (mtile << 8); pbase[e] = exclusive prefix of raw counts (scores
// rows are packed per-expert in list order). All LDS-indexed (no scratch, rule #20).
__global__ void tilelist_k(const int* __restrict__ counts, int* __restrict__ tiles,
                           int* __restrict__ ntiles, int* __restrict__ pbase) {
  __shared__ int tc[16], pb[16];
  int t = threadIdx.x;   // 64 threads
  if (t < 16) tc[t] = (counts[t * 16] + 127) >> 7;
  __syncthreads();
  if (t == 0) {
    int s = 0;
    for (int e = 0; e < 16; e++) { pb[e] = s; s += tc[e]; }
    *ntiles = s;
    int s2 = 0;
    for (int e = 0; e < 16; e++) { pbase[e] = s2; s2 += counts[e * 16]; }
  }
  __syncthreads();
  if (t < 16) {
    int b = pb[t], n = tc[t];
    for (int i = 0; i < n; i++) tiles[b + i] = t | (i << 8);
  }
}

// ---------------- grouped GEMM: T3+T4 pipelined (R14 core), pk-bf16 atomics ---------
// Core = R14 best (429us): BK=64, 2 LDS buffers [2][128][64] (128B rows, 8-chunk XOR,
// 0 conflicts), STAGE(next) -> s_waitcnt vmcnt(8) (next-buf loads IN FLIGHT) ->
// s_barrier -> COMPUTE(cur) -> s_barrier; never vmcnt(0) in main loop.
// PASS 2: A = Xbf gathered by token; B = keysT; AK=1024;
//         epilogue aff*silu -> bf16 scores, contiguous list-order rows.
// PASS 3: A = scores (contiguous); B = valuesT; AK=512;
//         epilogue: global_atomic_pk_add_bf16 into bf16 accum buffer (2 cols/atomic
//         via __shfl_xor pairing) -> HALVES atomic op count (50.3M -> 25.2M) and RMW
//         bytes vs f32 atomicAdd (R14 counter: WRITE 196MB = 6x32MB unmerged).
template<int AK, int PASS>
__global__ __launch_bounds__(256, 2) void moe_gemm_k(
    const u16* __restrict__ Abase, const u16* __restrict__ Bbase,
    const int* __restrict__ counts, const int* __restrict__ tokk,
    const float* __restrict__ affl, const int* __restrict__ tiles,
    const int* __restrict__ ntiles, const int* __restrict__ pbase,
    u16* __restrict__ scores_out) {
  int slot = blockIdx.y;
  if (slot >= *ntiles) return;
  int desc = tiles[slot];
  int e = desc & 15;
  int m0 = (desc >> 8) << 7;
  int cnt = counts[e * 16];
  int pbe = pbase[e];
  int n0 = blockIdx.x * 128;
  int t = threadIdx.x;
  int lane = t & 63, w = t >> 6;
  int wr = w >> 1, wc = w & 1;   // 2x2 waves, each 64x64

  __shared__ u16 Al[2][128][64];   // double-buffered; linear (global_load_lds dest)
  __shared__ u16 Bl[2][128][64];

  const int* tl = tokk + e * TOK_N + m0;
  const float* al = affl + e * TOK_N + m0;
  const u16* Bp = Bbase + (size_t)e * 524288;

  f32x4 acc[4][4];
  #pragma unroll
  for (int m = 0; m < 4; m++)
    #pragma unroll
    for (int n = 0; n < 4; n++)
      acc[m][n] = (f32x4){0.f, 0.f, 0.f, 0.f};

  // staging geometry: per r (r<4), wave w stages rows [r*32+w*8, +8): 64 lanes x 16B = 1KB.
  // lane -> row = base + (lane>>3), chunk j = lane&7; source chunk pre-swizzled j^(row&7).
  int jj = lane & 7, rl = lane >> 3;
  const u16* ag[4]; const u16* bg[4];
  #pragma unroll
  for (int r = 0; r < 4; r++) {
    int row = r * 32 + w * 8 + rl;
    int lr = (m0 + row < cnt) ? row : 0;   // clamp to a valid row (masked at epilogue)
    int ar;
    if (PASS == 2) {
      int tk = tl[lr];
      ar = tk >> 3;                        // gather X row by token
    } else {
      ar = pbe + m0 + lr;                  // contiguous list-order scores row
    }
    int cs = (jj ^ (row & 7)) * 8;         // swizzled source element offset
    ag[r] = Abase + (size_t)ar * AK + cs;
    bg[r] = Bp + (size_t)(n0 + row) * AK + cs;
  }

#define STAGE(B, K0)                                             \
  _Pragma("unroll")                                              \
  for (int r = 0; r < 4; r++) {                                  \
    gload_lds16(ag[r] + (K0), &Al[B][r * 32 + w * 8][0]);        \
    gload_lds16(bg[r] + (K0), &Bl[B][r * 32 + w * 8][0]);        \
  }

#define COMPUTE(B)                                                         \
  _Pragma("unroll")                                                        \
  for (int kk = 0; kk < 2; kk++) {                                         \
    int lc = kk * 4 + (lane >> 4);                                         \
    short8 af[4], bf[4];                                                   \
    _Pragma("unroll")                                                      \
    for (int m = 0; m < 4; m++) {                                          \
      int row = wr * 64 + m * 16 + (lane & 15);                            \
      af[m] = *(const short8*)&Al[B][row][(lc ^ (row & 7)) * 8];           \
    }                                                                      \
    _Pragma("unroll")                                                      \
    for (int n = 0; n < 4; n++) {                                          \
      int row = wc * 64 + n * 16 + (lane & 15);                            \
      bf[n] = *(const short8*)&Bl[B][row][(lc ^ (row & 7)) * 8];           \
    }                                                                      \
    _Pragma("unroll")                                                      \
    for (int m = 0; m < 4; m++)                                            \
      _Pragma("unroll")                                                    \
      for (int n = 0; n < 4; n++)                                          \
        acc[m][n] = __builtin_amdgcn_mfma_f32_16x16x32_bf16(af[m], bf[n],  \
                                                            acc[m][n], 0, 0, 0); \
  }

#define VWAIT8 asm volatile("s_waitcnt vmcnt(8)" ::: "memory")
#define VWAIT0 asm volatile("s_waitcnt vmcnt(0)" ::: "memory")
#define BARR  __builtin_amdgcn_s_barrier()
#define PIN   __builtin_amdgcn_sched_barrier(0)

  constexpr int NIT = AK / 64;   // 16 (pass2) / 8 (pass3) -- even, >= 4
  STAGE(0, 0)                    // 8 loads in flight (buf0)
  #pragma unroll 1
  for (int it = 0; it < NIT - 2; it += 2) {
    STAGE(1, (it + 1) * 64)      // +8 -> 16 in flight
    VWAIT8; BARR; PIN;           // buf0 done everywhere; buf1 loads still flying
    COMPUTE(0)
    BARR; PIN;                   // all waves done reading buf0 -> safe to overwrite
    STAGE(0, (it + 2) * 64)
    VWAIT8; BARR; PIN;           // buf1 done; buf0-next still flying
    COMPUTE(1)
    BARR; PIN;
  }
  // peeled tail: it = NIT-2
  STAGE(1, (NIT - 1) * 64)
  VWAIT8; BARR; PIN;
  COMPUTE(0)
  BARR; PIN;
  VWAIT0; BARR; PIN;             // drain buf1's loads
  COMPUTE(1)

#undef STAGE
#undef COMPUTE
#undef VWAIT8
#undef VWAIT0
#undef BARR
#undef PIN

  int cbase = n0 + wc * 64 + (lane & 15);
  #pragma unroll
  for (int m = 0; m < 4; m++) {
    int rbase = wr * 64 + m * 16 + ((lane >> 4) << 2);   // C/D: col=lane&15, row=(lane>>4)*4+q
    #pragma unroll
    for (int q = 0; q < 4; q++) {
      int row = rbase + q;
      if (m0 + row >= cnt) continue;
      if (PASS == 2) {
        float aff = al[row];
        size_t base = (size_t)(pbe + m0 + row) * FEXP;   // contiguous list-order row
        #pragma unroll
        for (int n = 0; n < 4; n++) {
          float v = acc[m][n][q];
          float s = aff * v / (1.f + expf(-v));   // aff * silu(v)
          scores_out[base + cbase + n * 16] = f2bf(s);
        }
      } else {
        // pk-bf16 atomic accumulate: pair columns (c, c+1) across lanes (L, L^1).
        // Both lanes of a pair share row (row indep of lane&15) -> convergent shfl.
        int tk = tl[row];
        size_t base = (size_t)(tk >> 3) * DMODEL;
        #pragma unroll
        for (int n = 0; n < 4; n++) {
          float v = acc[m][n][q];
          float v2 = __shfl_xor(v, 1);
          if (!(lane & 1)) {
            unsigned pk = (unsigned)f2bf(v) | ((unsigned)f2bf(v2) << 16);
            u16* ap = scores_out + base + cbase + n * 16;   // even col, 4B-aligned
            asm volatile("global_atomic_pk_add_bf16 %0, %1, off"
                         :: "v"((unsigned long long)(uintptr_t)ap), "v"(pk)
                         : "memory");
          }
        }
      }
    }
  }
}

extern "C" void kernel_launch(void* const* d_in, const int* in_sizes, int n_in,
                              void* d_out, int out_size, void* d_ws, size_t ws_size,
                              hipStream_t stream) {
  (void)in_sizes; (void)n_in; (void)out_size; (void)ws_size;
  const float* token_stream    = (const float*)d_in[0];
  const float* selection_input = (const float*)d_in[1];
  const float* keys_w          = (const float*)d_in[2];
  const float* values_w        = (const float*)d_in[3];
  const float* expert_sel      = (const float*)d_in[4];
  const float* bias_ffn        = (const float*)d_in[5];

  float* out     = (float*)d_out;                       // [8192][1024] f32
  float* out_sel = out + (size_t)TOK_N * DMODEL;        // [8192][6] as float

  char* ws = (char*)d_ws;
  u16*      Xbf      = (u16*)(ws + 0);                  // 16 MB (reused as bf16 out-accum)
  u16*      keysT    = (u16*)(ws + 16777216);           // 16 MB  [e][512][1024]
  u16*      valuesT  = (u16*)(ws + 33554432);           // 16 MB  [e][1024][512]
  u16*      scoresbf = (u16*)(ws + 50331648);           // 48 MB  [49152 list-order][512]
  int*      counts   = (int*)(ws + 100663296);          // 1 KB (padded, e -> counts[e*16])
  int*      tokk     = (int*)(ws + 100664320);          // 512 KB
  float*    affl     = (float*)(ws + 101188608);        // 512 KB
  unsigned* sel_pack = (unsigned*)(ws + 101712896);     // 32 KB
  float*    aff6     = (float*)(ws + 101745664);        // 192 KB
  int*      tiles    = (int*)(ws + 101942272);          // 4 KB
  int*      ntiles   = (int*)(ws + 101946368);          // 4 B
  int*      pbase    = (int*)(ws + 101946432);          // 64 B
  u16*      outbf    = Xbf;                             // alias: Xbf dead after pass-2

  hipMemsetAsync(counts, 0, 1024, stream);

  cast_bf16_k<<<4096, 256, 0, stream>>>(token_stream, Xbf, TOK_N * DMODEL / 8);
  transpose_cast_k<<<dim3(16, 32, 16), dim3(32, 8), 0, stream>>>(keys_w, keysT, 1024, 512);
  transpose_cast_k<<<dim3(32, 16, 16), dim3(32, 8), 0, stream>>>(values_w, valuesT, 512, 1024);

  routing_k<<<TOK_N, 256, 0, stream>>>(selection_input, expert_sel, bias_ffn,
                                       out_sel, sel_pack, aff6);
  scatter_k<<<TOK_N / 256, 256, 0, stream>>>(sel_pack, aff6, counts, tokk, affl);
  tilelist_k<<<1, 64, 0, stream>>>(counts, tiles, ntiles, pbase);

  // scores = aff * silu(X @ K[e]):  M<=49152, N=512, K=1024
  moe_gemm_k<1024, 2><<<dim3(4, MAXTILES), 256, 0, stream>>>(Xbf, keysT, counts, tokk, affl,
                                                             tiles, ntiles, pbase, scoresbf);
  // Xbf dead now -> becomes bf16 out-accumulator, zeroed (stream-ordered after pass-2)
  hipMemsetAsync(outbf, 0, (size_t)TOK_N * DMODEL * sizeof(u16), stream);
  // outbf += scores @ V[e] (pk-bf16 atomics):  M<=49152, N=1024, K=512
  moe_gemm_k<512, 3><<<dim3(8, MAXTILES), 256, 0, stream>>>(scoresbf, valuesT, counts, tokk, affl,
                                                            tiles, ntiles, pbase, outbf);
  // f32 output
  cast_out_k<<<4096, 256, 0, stream>>>(outbf, out);
}

// Round 18
// 416.012 us; speedup vs baseline: 1.0957x; 1.0957x over previous
//
#include <hip/hip_runtime.h>

typedef short short8 __attribute__((ext_vector_type(8)));
typedef float f32x4 __attribute__((ext_vector_type(4)));
typedef unsigned short u16;

#define TOK_N 8192      // B*S
#define DMODEL 1024
#define NEXP 16
#define FEXP 512
#define NROUTED 14
#define KSEL 6
#define MAXTILES 400    // sum ceil(cnt_e/128) <= 49152/128 + 16 (divisible by 8)

__device__ __forceinline__ u16 f2bf(float f) {
  unsigned u = __float_as_uint(f);
  u += 0x7fff + ((u >> 16) & 1);   // round-to-nearest-even
  return (u16)(u >> 16);
}

typedef const __attribute__((address_space(1))) unsigned int* gas_p;
typedef __attribute__((address_space(3))) unsigned int* las_p;
// wave-uniform LDS base + lane*16; per-lane global src (16B each)
__device__ __forceinline__ void gload_lds16(const void* g, void* l) {
  __builtin_amdgcn_global_load_lds((gas_p)g, (las_p)l, 16, 0, 0);
}

// ---------------- cast f32 -> bf16 (token stream) ----------------
__global__ void cast_bf16_k(const float* __restrict__ in, u16* __restrict__ out, int n8) {
  int i = blockIdx.x * blockDim.x + threadIdx.x;
  if (i >= n8) return;
  const float4* p = (const float4*)(in + (size_t)i * 8);
  float4 a = p[0], b = p[1];
  short8 v;
  v[0] = (short)f2bf(a.x); v[1] = (short)f2bf(a.y); v[2] = (short)f2bf(a.z); v[3] = (short)f2bf(a.w);
  v[4] = (short)f2bf(b.x); v[5] = (short)f2bf(b.y); v[6] = (short)f2bf(b.z); v[7] = (short)f2bf(b.w);
  *(short8*)(out + (size_t)i * 8) = v;
}

// ------------- transpose + cast: in [e][R][C] f32 -> out [e][C][R] bf16 -------------
__global__ void transpose_cast_k(const float* __restrict__ in, u16* __restrict__ out, int R, int C) {
  __shared__ u16 tile[32][33];
  int e = blockIdx.z;
  int c0 = blockIdx.x * 32, r0 = blockIdx.y * 32;
  int x = threadIdx.x, y = threadIdx.y;   // block (32,8)
  const float* ip = in + ((size_t)e * R + r0) * C + c0;
  #pragma unroll
  for (int i = 0; i < 4; i++)
    tile[y + 8 * i][x] = f2bf(ip[(size_t)(y + 8 * i) * C + x]);
  __syncthreads();
  u16* op = out + ((size_t)e * C + c0) * R + r0;
  #pragma unroll
  for (int i = 0; i < 4; i++)
    op[(size_t)(y + 8 * i) * R + x] = tile[x][y + 8 * i];
}

// ---------------- routing pass A: logits, sigmoid, stable top-4 (NO global atomics) ----
__global__ void routing_k(const float* __restrict__ selin, const float* __restrict__ esel,
                          const float* __restrict__ bias, float* __restrict__ out_sel,
                          unsigned* __restrict__ sel_pack, float* __restrict__ aff6) {
  int tok = blockIdx.x;
  int t = threadIdx.x;
  int e = t & 15, chunk = t >> 4;          // 16 experts x 16 chunks of 64 elems
  const float4* r4 = (const float4*)(selin + (size_t)tok * DMODEL + chunk * 64);
  const float4* w4 = (const float4*)(esel + (size_t)e * DMODEL + chunk * 64);
  float p = 0.f;
  #pragma unroll
  for (int i = 0; i < 16; i++) {
    float4 a = r4[i], b = w4[i];
    p += a.x * b.x + a.y * b.y + a.z * b.z + a.w * b.w;
  }
  __shared__ float part[16][17];
  __shared__ float aff[16];
  __shared__ float lbias[NROUTED];
  if (t < NROUTED) lbias[t] = bias[t];
  part[chunk][e] = p;
  __syncthreads();
  if (t < 16) {
    float s = 0.f;
    #pragma unroll
    for (int c = 0; c < 16; c++) s += part[c][t];
    aff[t] = 1.f / (1.f + expf(-s));
  }
  __syncthreads();
  if (t == 0) {
    unsigned pack = 0;
    unsigned taken = 0;
    #pragma unroll
    for (int k = 0; k < 4; k++) {
      float best = -3.4e38f; int bi = 0;
      for (int q = 0; q < NROUTED; q++) {
        if (taken & (1u << q)) continue;
        float v = aff[q] + lbias[q];
        if (v > best) { best = v; bi = q; }   // strict > => lowest index wins ties (top_k stable)
      }
      taken |= 1u << bi;
      pack |= (unsigned)bi << (4 * k);
      out_sel[(size_t)tok * KSEL + k] = (float)bi;
      aff6[(size_t)tok * KSEL + k] = aff[bi];
    }
    pack |= 14u << 16; pack |= 15u << 20;
    out_sel[(size_t)tok * KSEL + 4] = 14.f;
    out_sel[(size_t)tok * KSEL + 5] = 15.f;
    aff6[(size_t)tok * KSEL + 4] = aff[14];
    aff6[(size_t)tok * KSEL + 5] = aff[15];
    sel_pack[tok] = pack;
  }
}

// ---------------- routing pass B: hierarchical scatter into per-expert lists ----------
// counts padded: expert e lives at counts[e*16] (64B stride -> no cache-line sharing)
__global__ void scatter_k(const unsigned* __restrict__ sel_pack, const float* __restrict__ aff6,
                          int* __restrict__ counts, int* __restrict__ tokk,
                          float* __restrict__ affl) {
  __shared__ int lcnt[16], lbase[16], lcur[16];
  int t = threadIdx.x;
  int tok = blockIdx.x * 256 + t;
  if (t < 16) lcnt[t] = 0;
  __syncthreads();
  unsigned pack = sel_pack[tok];
  int eid[KSEL];
  #pragma unroll
  for (int k = 0; k < KSEL; k++) {
    eid[k] = (pack >> (4 * k)) & 15;
    atomicAdd(&lcnt[eid[k]], 1);
  }
  __syncthreads();
  if (t < 16) {
    lbase[t] = atomicAdd(&counts[t * 16], lcnt[t]);
    lcur[t] = 0;
  }
  __syncthreads();
  #pragma unroll
  for (int k = 0; k < KSEL; k++) {
    int e = eid[k];
    int slot = lbase[e] + atomicAdd(&lcur[e], 1);
    tokk[e * TOK_N + slot] = tok * 8 + k;
    affl[e * TOK_N + slot] = aff6[(size_t)tok * KSEL + k];
  }
}

// ---------------- build compact tile list + per-expert prefix base, parallel ----------
// tiles[slot] = e | (mtile << 8); pbase[e] = exclusive prefix of raw counts (scores
// rows are packed per-expert in list order). All LDS-indexed (no scratch, rule #20).
__global__ void tilelist_k(const int* __restrict__ counts, int* __restrict__ tiles,
                           int* __restrict__ ntiles, int* __restrict__ pbase) {
  __shared__ int tc[16], pb[16];
  int t = threadIdx.x;   // 64 threads
  if (t < 16) tc[t] = (counts[t * 16] + 127) >> 7;
  __syncthreads();
  if (t == 0) {
    int s = 0;
    for (int e = 0; e < 16; e++) { pb[e] = s; s += tc[e]; }
    *ntiles = s;
    int s2 = 0;
    for (int e = 0; e < 16; e++) { pbase[e] = s2; s2 += counts[e * 16]; }
  }
  __syncthreads();
  if (t < 16) {
    int b = pb[t], n = tc[t];
    for (int i = 0; i < n; i++) tiles[b + i] = t | (i << 8);
  }
}

// ---------------- grouped GEMM: R14 core + XCD-coherent y-sibling remap --------------
// Core = R14 best (429us): BK=64, 2 LDS bufs [2][128][64], 8-chunk XOR swizzle
// (0 conflicts), counted-vmcnt schedule: STAGE(next) -> vmcnt(8) -> s_barrier ->
// COMPUTE(cur) -> s_barrier; never vmcnt(0) in main loop. f32 atomicAdd epilogue.
// NEW (R18): 1D grid, remap p -> (slot,y) with slot=(p&7)+8*(p/(8*NY)), y=(p/8)%NY.
// HW dispatch round-robins p across XCDs (p%8), so ALL NY y-siblings of slot s land
// on XCD s%8 within an 8*NY dispatch window -> the shared gathered A-tile misses L2
// ONCE instead of NY times (R17 counter: FETCH 207MB = 6.5x unique data; the NY
// siblings previously sat on different, non-coherent L2s). Bijective: MAXTILES%8==0.
// PASS 2: A = Xbf gathered by token; B = keysT; AK=1024; NY=4;
//         epilogue aff*silu -> bf16 scores, contiguous list-order rows.
// PASS 3: A = scores (contiguous, no gather); B = valuesT; AK=512; NY=8;
//         epilogue: f32 atomicAdd scatter into out[tok][1024].
template<int AK, int PASS, int NY>
__global__ __launch_bounds__(256, 2) void moe_gemm_k(
    const u16* __restrict__ Abase, const u16* __restrict__ Bbase,
    const int* __restrict__ counts, const int* __restrict__ tokk,
    const float* __restrict__ affl, const int* __restrict__ tiles,
    const int* __restrict__ ntiles, const int* __restrict__ pbase,
    u16* __restrict__ scores_out, float* __restrict__ out) {
  int p = blockIdx.x;
  int slot = (p & 7) + 8 * (p / (8 * NY));
  int y = (p >> 3) % NY;
  if (slot >= *ntiles) return;
  int desc = tiles[slot];
  int e = desc & 15;
  int m0 = (desc >> 8) << 7;
  int cnt = counts[e * 16];
  int pbe = pbase[e];
  int n0 = y * 128;
  int t = threadIdx.x;
  int lane = t & 63, w = t >> 6;
  int wr = w >> 1, wc = w & 1;   // 2x2 waves, each 64x64

  __shared__ u16 Al[2][128][64];   // double-buffered; linear (global_load_lds dest)
  __shared__ u16 Bl[2][128][64];

  const int* tl = tokk + e * TOK_N + m0;
  const float* al = affl + e * TOK_N + m0;
  const u16* Bp = Bbase + (size_t)e * 524288;

  f32x4 acc[4][4];
  #pragma unroll
  for (int m = 0; m < 4; m++)
    #pragma unroll
    for (int n = 0; n < 4; n++)
      acc[m][n] = (f32x4){0.f, 0.f, 0.f, 0.f};

  // staging geometry: per r (r<4), wave w stages rows [r*32+w*8, +8): 64 lanes x 16B = 1KB.
  // lane -> row = base + (lane>>3), chunk j = lane&7; source chunk pre-swizzled j^(row&7).
  int jj = lane & 7, rl = lane >> 3;
  const u16* ag[4]; const u16* bg[4];
  #pragma unroll
  for (int r = 0; r < 4; r++) {
    int row = r * 32 + w * 8 + rl;
    int lr = (m0 + row < cnt) ? row : 0;   // clamp to a valid row (masked at epilogue)
    int ar;
    if (PASS == 2) {
      int tk = tl[lr];
      ar = tk >> 3;                        // gather X row by token
    } else {
      ar = pbe + m0 + lr;                  // contiguous list-order scores row
    }
    int cs = (jj ^ (row & 7)) * 8;         // swizzled source element offset
    ag[r] = Abase + (size_t)ar * AK + cs;
    bg[r] = Bp + (size_t)(n0 + row) * AK + cs;
  }

#define STAGE(B, K0)                                             \
  _Pragma("unroll")                                              \
  for (int r = 0; r < 4; r++) {                                  \
    gload_lds16(ag[r] + (K0), &Al[B][r * 32 + w * 8][0]);        \
    gload_lds16(bg[r] + (K0), &Bl[B][r * 32 + w * 8][0]);        \
  }

#define COMPUTE(B)                                                         \
  _Pragma("unroll")                                                        \
  for (int kk = 0; kk < 2; kk++) {                                         \
    int lc = kk * 4 + (lane >> 4);                                         \
    short8 af[4], bf[4];                                                   \
    _Pragma("unroll")                                                      \
    for (int m = 0; m < 4; m++) {                                          \
      int row = wr * 64 + m * 16 + (lane & 15);                            \
      af[m] = *(const short8*)&Al[B][row][(lc ^ (row & 7)) * 8];           \
    }                                                                      \
    _Pragma("unroll")                                                      \
    for (int n = 0; n < 4; n++) {                                          \
      int row = wc * 64 + n * 16 + (lane & 15);                            \
      bf[n] = *(const short8*)&Bl[B][row][(lc ^ (row & 7)) * 8];           \
    }                                                                      \
    _Pragma("unroll")                                                      \
    for (int m = 0; m < 4; m++)                                            \
      _Pragma("unroll")                                                    \
      for (int n = 0; n < 4; n++)                                          \
        acc[m][n] = __builtin_amdgcn_mfma_f32_16x16x32_bf16(af[m], bf[n],  \
                                                            acc[m][n], 0, 0, 0); \
  }

#define VWAIT8 asm volatile("s_waitcnt vmcnt(8)" ::: "memory")
#define VWAIT0 asm volatile("s_waitcnt vmcnt(0)" ::: "memory")
#define BARR  __builtin_amdgcn_s_barrier()
#define PIN   __builtin_amdgcn_sched_barrier(0)

  constexpr int NIT = AK / 64;   // 16 (pass2) / 8 (pass3) -- even, >= 4
  STAGE(0, 0)                    // 8 loads in flight (buf0)
  #pragma unroll 1
  for (int it = 0; it < NIT - 2; it += 2) {
    STAGE(1, (it + 1) * 64)      // +8 -> 16 in flight
    VWAIT8; BARR; PIN;           // buf0 done everywhere; buf1 loads still flying
    COMPUTE(0)
    BARR; PIN;                   // all waves done reading buf0 -> safe to overwrite
    STAGE(0, (it + 2) * 64)
    VWAIT8; BARR; PIN;           // buf1 done; buf0-next still flying
    COMPUTE(1)
    BARR; PIN;
  }
  // peeled tail: it = NIT-2
  STAGE(1, (NIT - 1) * 64)
  VWAIT8; BARR; PIN;
  COMPUTE(0)
  BARR; PIN;
  VWAIT0; BARR; PIN;             // drain buf1's loads
  COMPUTE(1)

#undef STAGE
#undef COMPUTE
#undef VWAIT8
#undef VWAIT0
#undef BARR
#undef PIN

  int cbase = n0 + wc * 64 + (lane & 15);
  #pragma unroll
  for (int m = 0; m < 4; m++) {
    int rbase = wr * 64 + m * 16 + ((lane >> 4) << 2);   // C/D: col=lane&15, row=(lane>>4)*4+q
    #pragma unroll
    for (int q = 0; q < 4; q++) {
      int row = rbase + q;
      if (m0 + row >= cnt) continue;
      if (PASS == 2) {
        float aff = al[row];
        size_t base = (size_t)(pbe + m0 + row) * FEXP;   // contiguous list-order row
        #pragma unroll
        for (int n = 0; n < 4; n++) {
          float v = acc[m][n][q];
          float s = aff * v / (1.f + expf(-v));   // aff * silu(v)
          scores_out[base + cbase + n * 16] = f2bf(s);
        }
      } else {
        int tk = tl[row];
        size_t base = (size_t)(tk >> 3) * DMODEL;
        #pragma unroll
        for (int n = 0; n < 4; n++)
          atomicAdd(&out[base + cbase + n * 16], acc[m][n][q]);
      }
    }
  }
}

extern "C" void kernel_launch(void* const* d_in, const int* in_sizes, int n_in,
                              void* d_out, int out_size, void* d_ws, size_t ws_size,
                              hipStream_t stream) {
  (void)in_sizes; (void)n_in; (void)out_size; (void)ws_size;
  const float* token_stream    = (const float*)d_in[0];
  const float* selection_input = (const float*)d_in[1];
  const float* keys_w          = (const float*)d_in[2];
  const float* values_w        = (const float*)d_in[3];
  const float* expert_sel      = (const float*)d_in[4];
  const float* bias_ffn        = (const float*)d_in[5];

  float* out     = (float*)d_out;                       // [8192][1024] f32
  float* out_sel = out + (size_t)TOK_N * DMODEL;        // [8192][6] as float

  char* ws = (char*)d_ws;
  u16*      Xbf      = (u16*)(ws + 0);                  // 16 MB
  u16*      keysT    = (u16*)(ws + 16777216);           // 16 MB  [e][512][1024]
  u16*      valuesT  = (u16*)(ws + 33554432);           // 16 MB  [e][1024][512]
  u16*      scoresbf = (u16*)(ws + 50331648);           // 48 MB  [49152 list-order][512]
  int*      counts   = (int*)(ws + 100663296);          // 1 KB (padded, e -> counts[e*16])
  int*      tokk     = (int*)(ws + 100664320);          // 512 KB
  float*    affl     = (float*)(ws + 101188608);        // 512 KB
  unsigned* sel_pack = (unsigned*)(ws + 101712896);     // 32 KB
  float*    aff6     = (float*)(ws + 101745664);        // 192 KB
  int*      tiles    = (int*)(ws + 101942272);          // 4 KB
  int*      ntiles   = (int*)(ws + 101946368);          // 4 B
  int*      pbase    = (int*)(ws + 101946432);          // 64 B

  hipMemsetAsync(out, 0, (size_t)TOK_N * DMODEL * sizeof(float), stream);
  hipMemsetAsync(counts, 0, 1024, stream);

  cast_bf16_k<<<4096, 256, 0, stream>>>(token_stream, Xbf, TOK_N * DMODEL / 8);
  transpose_cast_k<<<dim3(16, 32, 16), dim3(32, 8), 0, stream>>>(keys_w, keysT, 1024, 512);
  transpose_cast_k<<<dim3(32, 16, 16), dim3(32, 8), 0, stream>>>(values_w, valuesT, 512, 1024);

  routing_k<<<TOK_N, 256, 0, stream>>>(selection_input, expert_sel, bias_ffn,
                                       out_sel, sel_pack, aff6);
  scatter_k<<<TOK_N / 256, 256, 0, stream>>>(sel_pack, aff6, counts, tokk, affl);
  tilelist_k<<<1, 64, 0, stream>>>(counts, tiles, ntiles, pbase);

  // scores = aff * silu(X @ K[e]):  M<=49152, N=512, K=1024
  moe_gemm_k<1024, 2, 4><<<MAXTILES * 4, 256, 0, stream>>>(Xbf, keysT, counts, tokk, affl,
                                                           tiles, ntiles, pbase,
                                                           scoresbf, nullptr);
  // out += scores @ V[e]:          M<=49152, N=1024, K=512
  moe_gemm_k<512, 3, 8><<<MAXTILES * 8, 256, 0, stream>>>(scoresbf, valuesT, counts, tokk, affl,
                                                          tiles, ntiles, pbase,
                                                          nullptr, out);
}

// Round 22
// 411.028 us; speedup vs baseline: 1.1090x; 1.0121x over previous
//
#include <hip/hip_runtime.h>

typedef short short8 __attribute__((ext_vector_type(8)));
typedef float f32x4 __attribute__((ext_vector_type(4)));
typedef unsigned short u16;

#define TOK_N 8192      // B*S
#define DMODEL 1024
#define NEXP 16
#define FEXP 512
#define NROUTED 14
#define KSEL 6
#define MAXTILES 400    // sum ceil(cnt_e/128) <= 49152/128 + 16 (divisible by 8)

__device__ __forceinline__ u16 f2bf(float f) {
  unsigned u = __float_as_uint(f);
  u += 0x7fff + ((u >> 16) & 1);   // round-to-nearest-even
  return (u16)(u >> 16);
}

typedef const __attribute__((address_space(1))) unsigned int* gas_p;
typedef __attribute__((address_space(3))) unsigned int* las_p;
// wave-uniform LDS base + lane*16; per-lane global src (16B each)
__device__ __forceinline__ void gload_lds16(const void* g, void* l) {
  __builtin_amdgcn_global_load_lds((gas_p)g, (las_p)l, 16, 0, 0);
}

// ---------------- cast f32 -> bf16 (token stream) ----------------
__global__ void cast_bf16_k(const float* __restrict__ in, u16* __restrict__ out, int n8) {
  int i = blockIdx.x * blockDim.x + threadIdx.x;
  if (i >= n8) return;
  const float4* p = (const float4*)(in + (size_t)i * 8);
  float4 a = p[0], b = p[1];
  short8 v;
  v[0] = (short)f2bf(a.x); v[1] = (short)f2bf(a.y); v[2] = (short)f2bf(a.z); v[3] = (short)f2bf(a.w);
  v[4] = (short)f2bf(b.x); v[5] = (short)f2bf(b.y); v[6] = (short)f2bf(b.z); v[7] = (short)f2bf(b.w);
  *(short8*)(out + (size_t)i * 8) = v;
}

// ------------- transpose + cast: in [e][R][C] f32 -> out [e][C][R] bf16 -------------
__global__ void transpose_cast_k(const float* __restrict__ in, u16* __restrict__ out, int R, int C) {
  __shared__ u16 tile[32][33];
  int e = blockIdx.z;
  int c0 = blockIdx.x * 32, r0 = blockIdx.y * 32;
  int x = threadIdx.x, y = threadIdx.y;   // block (32,8)
  const float* ip = in + ((size_t)e * R + r0) * C + c0;
  #pragma unroll
  for (int i = 0; i < 4; i++)
    tile[y + 8 * i][x] = f2bf(ip[(size_t)(y + 8 * i) * C + x]);
  __syncthreads();
  u16* op = out + ((size_t)e * C + c0) * R + r0;
  #pragma unroll
  for (int i = 0; i < 4; i++)
    op[(size_t)(y + 8 * i) * R + x] = tile[x][y + 8 * i];
}

// ---------------- routing pass A: logits, sigmoid, stable top-4 (NO global atomics) ----
__global__ void routing_k(const float* __restrict__ selin, const float* __restrict__ esel,
                          const float* __restrict__ bias, float* __restrict__ out_sel,
                          unsigned* __restrict__ sel_pack, float* __restrict__ aff6) {
  int tok = blockIdx.x;
  int t = threadIdx.x;
  int e = t & 15, chunk = t >> 4;          // 16 experts x 16 chunks of 64 elems
  const float4* r4 = (const float4*)(selin + (size_t)tok * DMODEL + chunk * 64);
  const float4* w4 = (const float4*)(esel + (size_t)e * DMODEL + chunk * 64);
  float p = 0.f;
  #pragma unroll
  for (int i = 0; i < 16; i++) {
    float4 a = r4[i], b = w4[i];
    p += a.x * b.x + a.y * b.y + a.z * b.z + a.w * b.w;
  }
  __shared__ float part[16][17];
  __shared__ float aff[16];
  __shared__ float lbias[NROUTED];
  if (t < NROUTED) lbias[t] = bias[t];
  part[chunk][e] = p;
  __syncthreads();
  if (t < 16) {
    float s = 0.f;
    #pragma unroll
    for (int c = 0; c < 16; c++) s += part[c][t];
    aff[t] = 1.f / (1.f + expf(-s));
  }
  __syncthreads();
  if (t == 0) {
    unsigned pack = 0;
    unsigned taken = 0;
    #pragma unroll
    for (int k = 0; k < 4; k++) {
      float best = -3.4e38f; int bi = 0;
      for (int q = 0; q < NROUTED; q++) {
        if (taken & (1u << q)) continue;
        float v = aff[q] + lbias[q];
        if (v > best) { best = v; bi = q; }   // strict > => lowest index wins ties (top_k stable)
      }
      taken |= 1u << bi;
      pack |= (unsigned)bi << (4 * k);
      out_sel[(size_t)tok * KSEL + k] = (float)bi;
      aff6[(size_t)tok * KSEL + k] = aff[bi];
    }
    pack |= 14u << 16; pack |= 15u << 20;
    out_sel[(size_t)tok * KSEL + 4] = 14.f;
    out_sel[(size_t)tok * KSEL + 5] = 15.f;
    aff6[(size_t)tok * KSEL + 4] = aff[14];
    aff6[(size_t)tok * KSEL + 5] = aff[15];
    sel_pack[tok] = pack;
  }
}

// ---------------- routing pass B: hierarchical scatter into per-expert lists ----------
// counts padded: expert e lives at counts[e*16] (64B stride -> no cache-line sharing)
__global__ void scatter_k(const unsigned* __restrict__ sel_pack, const float* __restrict__ aff6,
                          int* __restrict__ counts, int* __restrict__ tokk,
                          float* __restrict__ affl) {
  __shared__ int lcnt[16], lbase[16], lcur[16];
  int t = threadIdx.x;
  int tok = blockIdx.x * 256 + t;
  if (t < 16) lcnt[t] = 0;
  __syncthreads();
  unsigned pack = sel_pack[tok];
  int eid[KSEL];
  #pragma unroll
  for (int k = 0; k < KSEL; k++) {
    eid[k] = (pack >> (4 * k)) & 15;
    atomicAdd(&lcnt[eid[k]], 1);
  }
  __syncthreads();
  if (t < 16) {
    lbase[t] = atomicAdd(&counts[t * 16], lcnt[t]);
    lcur[t] = 0;
  }
  __syncthreads();
  #pragma unroll
  for (int k = 0; k < KSEL; k++) {
    int e = eid[k];
    int slot = lbase[e] + atomicAdd(&lcur[e], 1);
    tokk[e * TOK_N + slot] = tok * 8 + k;
    affl[e * TOK_N + slot] = aff6[(size_t)tok * KSEL + k];
  }
}

// ---------------- build compact tile list + per-expert prefix base, parallel ----------
// tiles[slot] = e | (mtile << 8); pbase[e] = exclusive prefix of raw counts (scores
// rows are packed per-expert in list order). All LDS-indexed (no scratch, rule #20).
__global__ void tilelist_k(const int* __restrict__ counts, int* __restrict__ tiles,
                           int* __restrict__ ntiles, int* __restrict__ pbase) {
  __shared__ int tc[16], pb[16];
  int t = threadIdx.x;   // 64 threads
  if (t < 16) tc[t] = (counts[t * 16] + 127) >> 7;
  __syncthreads();
  if (t == 0) {
    int s = 0;
    for (int e = 0; e < 16; e++) { pb[e] = s; s += tc[e]; }
    *ntiles = s;
    int s2 = 0;
    for (int e = 0; e < 16; e++) { pbase[e] = s2; s2 += counts[e * 16]; }
  }
  __syncthreads();
  if (t < 16) {
    int b = pb[t], n = tc[t];
    for (int i = 0; i < n; i++) tiles[b + i] = t | (i << 8);
  }
}

// ---------------- grouped GEMM: R18 core widened to 8 waves (4 waves/SIMD) -----------
// Identical tile (128x128xBK=64), LDS (2x32KB dbuf), XOR swizzle, counted-vmcnt
// schedule and XCD-coherent remap as R18 (best, 416us). ONE change: 512 threads /
// 8 waves (2Mx4N, each 64x32, acc[4][2]) -> 16 waves/CU = 4 waves/SIMD (was 2).
// R18 counters showed FETCH near-minimal but MfmaUtil 11% at occupancy 21% —
// latency-bound on wave-level TLP; doubling waves/SIMD is the direct fix (m114).
// Staging: wave w stages A+B rows [w*16,w*16+16) in 2+2 gloads (8 rows/instr,
// row&7 == lane>>3 -> same pre-swizzle algebra); counted wait becomes VWAIT4.
// PASS 2: A = Xbf gathered by token; B = keysT; AK=1024; NY=4;
//         epilogue aff*silu -> bf16 scores, contiguous list-order rows.
// PASS 3: A = scores (contiguous, no gather); B = valuesT; AK=512; NY=8;
//         epilogue: f32 atomicAdd scatter into out[tok][1024].
template<int AK, int PASS, int NY>
__global__ __launch_bounds__(512, 2) void moe_gemm_k(
    const u16* __restrict__ Abase, const u16* __restrict__ Bbase,
    const int* __restrict__ counts, const int* __restrict__ tokk,
    const float* __restrict__ affl, const int* __restrict__ tiles,
    const int* __restrict__ ntiles, const int* __restrict__ pbase,
    u16* __restrict__ scores_out, float* __restrict__ out) {
  int p = blockIdx.x;
  int slot = (p & 7) + 8 * (p / (8 * NY));
  int y = (p >> 3) % NY;
  if (slot >= *ntiles) return;
  int desc = tiles[slot];
  int e = desc & 15;
  int m0 = (desc >> 8) << 7;
  int cnt = counts[e * 16];
  int pbe = pbase[e];
  int n0 = y * 128;
  int t = threadIdx.x;
  int lane = t & 63, w = t >> 6;   // 8 waves
  int wr = w >> 2, wc = w & 3;     // 2x4 waves, each 64x32

  __shared__ u16 Al[2][128][64];   // double-buffered; linear (global_load_lds dest)
  __shared__ u16 Bl[2][128][64];

  const int* tl = tokk + e * TOK_N + m0;
  const float* al = affl + e * TOK_N + m0;
  const u16* Bp = Bbase + (size_t)e * 524288;

  f32x4 acc[4][2];
  #pragma unroll
  for (int m = 0; m < 4; m++)
    #pragma unroll
    for (int n = 0; n < 2; n++)
      acc[m][n] = (f32x4){0.f, 0.f, 0.f, 0.f};

  // staging geometry: wave w stages A+B rows [w*16, w*16+16), 8 rows per gload
  // (lane -> row = base + (lane>>3), chunk j = lane&7; row&7 == lane>>3).
  // Source chunk pre-swizzled j ^ (row&7) (rule #21: linear dest, swizzled src).
  int jj = lane & 7, rl = lane >> 3;
  const u16* ag[2]; const u16* bg[2];
  #pragma unroll
  for (int r = 0; r < 2; r++) {
    int row = w * 16 + r * 8 + rl;
    int lr = (m0 + row < cnt) ? row : 0;   // clamp to a valid row (masked at epilogue)
    int ar;
    if (PASS == 2) {
      int tk = tl[lr];
      ar = tk >> 3;                        // gather X row by token
    } else {
      ar = pbe + m0 + lr;                  // contiguous list-order scores row
    }
    int cs = (jj ^ (row & 7)) * 8;         // swizzled source element offset
    ag[r] = Abase + (size_t)ar * AK + cs;
    bg[r] = Bp + (size_t)(n0 + row) * AK + cs;
  }

#define STAGE(B, K0)                                             \
  _Pragma("unroll")                                              \
  for (int r = 0; r < 2; r++) {                                  \
    gload_lds16(ag[r] + (K0), &Al[B][w * 16 + r * 8][0]);        \
    gload_lds16(bg[r] + (K0), &Bl[B][w * 16 + r * 8][0]);        \
  }

#define COMPUTE(B)                                                         \
  _Pragma("unroll")                                                        \
  for (int kk = 0; kk < 2; kk++) {                                         \
    int lc = kk * 4 + (lane >> 4);                                         \
    short8 af[4], bf[2];                                                   \
    _Pragma("unroll")                                                      \
    for (int m = 0; m < 4; m++) {                                          \
      int row = wr * 64 + m * 16 + (lane & 15);                            \
      af[m] = *(const short8*)&Al[B][row][(lc ^ (row & 7)) * 8];           \
    }                                                                      \
    _Pragma("unroll")                                                      \
    for (int n = 0; n < 2; n++) {                                          \
      int row = wc * 32 + n * 16 + (lane & 15);                            \
      bf[n] = *(const short8*)&Bl[B][row][(lc ^ (row & 7)) * 8];           \
    }                                                                      \
    _Pragma("unroll")                                                      \
    for (int m = 0; m < 4; m++)                                            \
      _Pragma("unroll")                                                    \
      for (int n = 0; n < 2; n++)                                          \
        acc[m][n] = __builtin_amdgcn_mfma_f32_16x16x32_bf16(af[m], bf[n],  \
                                                            acc[m][n], 0, 0, 0); \
  }

#define VWAIT4 asm volatile("s_waitcnt vmcnt(4)" ::: "memory")
#define VWAIT0 asm volatile("s_waitcnt vmcnt(0)" ::: "memory")
#define BARR  __builtin_amdgcn_s_barrier()
#define PIN   __builtin_amdgcn_sched_barrier(0)

  constexpr int NIT = AK / 64;   // 16 (pass2) / 8 (pass3) -- even, >= 4
  STAGE(0, 0)                    // 4 loads in flight (buf0)
  #pragma unroll 1
  for (int it = 0; it < NIT - 2; it += 2) {
    STAGE(1, (it + 1) * 64)      // +4 -> 8 in flight
    VWAIT4; BARR; PIN;           // buf0 done everywhere; buf1 loads still flying
    COMPUTE(0)
    BARR; PIN;                   // all waves done reading buf0 -> safe to overwrite
    STAGE(0, (it + 2) * 64)
    VWAIT4; BARR; PIN;           // buf1 done; buf0-next still flying
    COMPUTE(1)
    BARR; PIN;
  }
  // peeled tail: it = NIT-2
  STAGE(1, (NIT - 1) * 64)
  VWAIT4; BARR; PIN;
  COMPUTE(0)
  BARR; PIN;
  VWAIT0; BARR; PIN;             // drain buf1's loads
  COMPUTE(1)

#undef STAGE
#undef COMPUTE
#undef VWAIT4
#undef VWAIT0
#undef BARR
#undef PIN

  int cbase = n0 + wc * 32 + (lane & 15);
  #pragma unroll
  for (int m = 0; m < 4; m++) {
    int rbase = wr * 64 + m * 16 + ((lane >> 4) << 2);   // C/D: col=lane&15, row=(lane>>4)*4+q
    #pragma unroll
    for (int q = 0; q < 4; q++) {
      int row = rbase + q;
      if (m0 + row >= cnt) continue;
      if (PASS == 2) {
        float aff = al[row];
        size_t base = (size_t)(pbe + m0 + row) * FEXP;   // contiguous list-order row
        #pragma unroll
        for (int n = 0; n < 2; n++) {
          float v = acc[m][n][q];
          float s = aff * v / (1.f + expf(-v));   // aff * silu(v)
          scores_out[base + cbase + n * 16] = f2bf(s);
        }
      } else {
        int tk = tl[row];
        size_t base = (size_t)(tk >> 3) * DMODEL;
        #pragma unroll
        for (int n = 0; n < 2; n++)
          atomicAdd(&out[base + cbase + n * 16], acc[m][n][q]);
      }
    }
  }
}

extern "C" void kernel_launch(void* const* d_in, const int* in_sizes, int n_in,
                              void* d_out, int out_size, void* d_ws, size_t ws_size,
                              hipStream_t stream) {
  (void)in_sizes; (void)n_in; (void)out_size; (void)ws_size;
  const float* token_stream    = (const float*)d_in[0];
  const float* selection_input = (const float*)d_in[1];
  const float* keys_w          = (const float*)d_in[2];
  const float* values_w        = (const float*)d_in[3];
  const float* expert_sel      = (const float*)d_in[4];
  const float* bias_ffn        = (const float*)d_in[5];

  float* out     = (float*)d_out;                       // [8192][1024] f32
  float* out_sel = out + (size_t)TOK_N * DMODEL;        // [8192][6] as float

  char* ws = (char*)d_ws;
  u16*      Xbf      = (u16*)(ws + 0);                  // 16 MB
  u16*      keysT    = (u16*)(ws + 16777216);           // 16 MB  [e][512][1024]
  u16*      valuesT  = (u16*)(ws + 33554432);           // 16 MB  [e][1024][512]
  u16*      scoresbf = (u16*)(ws + 50331648);           // 48 MB  [49152 list-order][512]
  int*      counts   = (int*)(ws + 100663296);          // 1 KB (padded, e -> counts[e*16])
  int*      tokk     = (int*)(ws + 100664320);          // 512 KB
  float*    affl     = (float*)(ws + 101188608);        // 512 KB
  unsigned* sel_pack = (unsigned*)(ws + 101712896);     // 32 KB
  float*    aff6     = (float*)(ws + 101745664);        // 192 KB
  int*      tiles    = (int*)(ws + 101942272);          // 4 KB
  int*      ntiles   = (int*)(ws + 101946368);          // 4 B
  int*      pbase    = (int*)(ws + 101946432);          // 64 B

  hipMemsetAsync(out, 0, (size_t)TOK_N * DMODEL * sizeof(float), stream);
  hipMemsetAsync(counts, 0, 1024, stream);

  cast_bf16_k<<<4096, 256, 0, stream>>>(token_stream, Xbf, TOK_N * DMODEL / 8);
  transpose_cast_k<<<dim3(16, 32, 16), dim3(32, 8), 0, stream>>>(keys_w, keysT, 1024, 512);
  transpose_cast_k<<<dim3(32, 16, 16), dim3(32, 8), 0, stream>>>(values_w, valuesT, 512, 1024);

  routing_k<<<TOK_N, 256, 0, stream>>>(selection_input, expert_sel, bias_ffn,
                                       out_sel, sel_pack, aff6);
  scatter_k<<<TOK_N / 256, 256, 0, stream>>>(sel_pack, aff6, counts, tokk, affl);
  tilelist_k<<<1, 64, 0, stream>>>(counts, tiles, ntiles, pbase);

  // scores = aff * silu(X @ K[e]):  M<=49152, N=512, K=1024
  moe_gemm_k<1024, 2, 4><<<MAXTILES * 4, 512, 0, stream>>>(Xbf, keysT, counts, tokk, affl,
                                                           tiles, ntiles, pbase,
                                                           scoresbf, nullptr);
  // out += scores @ V[e]:          M<=49152, N=1024, K=512
  moe_gemm_k<512, 3, 8><<<MAXTILES * 8, 512, 0, stream>>>(scoresbf, valuesT, counts, tokk, affl,
                                                          tiles, ntiles, pbase,
                                                          nullptr, out);
}

// Round 23
// 406.988 us; speedup vs baseline: 1.1200x; 1.0099x over previous
//
#include <hip/hip_runtime.h>

typedef short short8 __attribute__((ext_vector_type(8)));
typedef float f32x4 __attribute__((ext_vector_type(4)));
typedef unsigned short u16;

#define TOK_N 8192      // B*S
#define DMODEL 1024
#define NEXP 16
#define FEXP 512
#define NROUTED 14
#define KSEL 6
#define MAXTILES 400    // sum ceil(cnt_e/128) <= 49152/128 + 16 (divisible by 8)

__device__ __forceinline__ u16 f2bf(float f) {
  unsigned u = __float_as_uint(f);
  u += 0x7fff + ((u >> 16) & 1);   // round-to-nearest-even
  return (u16)(u >> 16);
}

typedef const __attribute__((address_space(1))) unsigned int* gas_p;
typedef __attribute__((address_space(3))) unsigned int* las_p;
// wave-uniform LDS base + lane*16; per-lane global src (16B each)
__device__ __forceinline__ void gload_lds16(const void* g, void* l) {
  __builtin_amdgcn_global_load_lds((gas_p)g, (las_p)l, 16, 0, 0);
}

// ---------------- cast f32 -> bf16 (token stream) ----------------
__global__ void cast_bf16_k(const float* __restrict__ in, u16* __restrict__ out, int n8) {
  int i = blockIdx.x * blockDim.x + threadIdx.x;
  if (i >= n8) return;
  const float4* p = (const float4*)(in + (size_t)i * 8);
  float4 a = p[0], b = p[1];
  short8 v;
  v[0] = (short)f2bf(a.x); v[1] = (short)f2bf(a.y); v[2] = (short)f2bf(a.z); v[3] = (short)f2bf(a.w);
  v[4] = (short)f2bf(b.x); v[5] = (short)f2bf(b.y); v[6] = (short)f2bf(b.z); v[7] = (short)f2bf(b.w);
  *(short8*)(out + (size_t)i * 8) = v;
}

// ------------- transpose + cast: in [e][R][C] f32 -> out [e][C][R] bf16 -------------
__global__ void transpose_cast_k(const float* __restrict__ in, u16* __restrict__ out, int R, int C) {
  __shared__ u16 tile[32][33];
  int e = blockIdx.z;
  int c0 = blockIdx.x * 32, r0 = blockIdx.y * 32;
  int x = threadIdx.x, y = threadIdx.y;   // block (32,8)
  const float* ip = in + ((size_t)e * R + r0) * C + c0;
  #pragma unroll
  for (int i = 0; i < 4; i++)
    tile[y + 8 * i][x] = f2bf(ip[(size_t)(y + 8 * i) * C + x]);
  __syncthreads();
  u16* op = out + ((size_t)e * C + c0) * R + r0;
  #pragma unroll
  for (int i = 0; i < 4; i++)
    op[(size_t)(y + 8 * i) * R + x] = tile[x][y + 8 * i];
}

// ---------------- routing pass A: logits, sigmoid, stable top-4 (NO global atomics) ----
__global__ void routing_k(const float* __restrict__ selin, const float* __restrict__ esel,
                          const float* __restrict__ bias, float* __restrict__ out_sel,
                          unsigned* __restrict__ sel_pack, float* __restrict__ aff6) {
  int tok = blockIdx.x;
  int t = threadIdx.x;
  int e = t & 15, chunk = t >> 4;          // 16 experts x 16 chunks of 64 elems
  const float4* r4 = (const float4*)(selin + (size_t)tok * DMODEL + chunk * 64);
  const float4* w4 = (const float4*)(esel + (size_t)e * DMODEL + chunk * 64);
  float p = 0.f;
  #pragma unroll
  for (int i = 0; i < 16; i++) {
    float4 a = r4[i], b = w4[i];
    p += a.x * b.x + a.y * b.y + a.z * b.z + a.w * b.w;
  }
  __shared__ float part[16][17];
  __shared__ float aff[16];
  __shared__ float lbias[NROUTED];
  if (t < NROUTED) lbias[t] = bias[t];
  part[chunk][e] = p;
  __syncthreads();
  if (t < 16) {
    float s = 0.f;
    #pragma unroll
    for (int c = 0; c < 16; c++) s += part[c][t];
    aff[t] = 1.f / (1.f + expf(-s));
  }
  __syncthreads();
  if (t == 0) {
    unsigned pack = 0;
    unsigned taken = 0;
    #pragma unroll
    for (int k = 0; k < 4; k++) {
      float best = -3.4e38f; int bi = 0;
      for (int q = 0; q < NROUTED; q++) {
        if (taken & (1u << q)) continue;
        float v = aff[q] + lbias[q];
        if (v > best) { best = v; bi = q; }   // strict > => lowest index wins ties (top_k stable)
      }
      taken |= 1u << bi;
      pack |= (unsigned)bi << (4 * k);
      out_sel[(size_t)tok * KSEL + k] = (float)bi;
      aff6[(size_t)tok * KSEL + k] = aff[bi];
    }
    pack |= 14u << 16; pack |= 15u << 20;
    out_sel[(size_t)tok * KSEL + 4] = 14.f;
    out_sel[(size_t)tok * KSEL + 5] = 15.f;
    aff6[(size_t)tok * KSEL + 4] = aff[14];
    aff6[(size_t)tok * KSEL + 5] = aff[15];
    sel_pack[tok] = pack;
  }
}

// ---------------- routing pass B: hierarchical scatter into per-expert lists ----------
// counts padded: expert e lives at counts[e*16] (64B stride -> no cache-line sharing)
__global__ void scatter_k(const unsigned* __restrict__ sel_pack, const float* __restrict__ aff6,
                          int* __restrict__ counts, int* __restrict__ tokk,
                          float* __restrict__ affl) {
  __shared__ int lcnt[16], lbase[16], lcur[16];
  int t = threadIdx.x;
  int tok = blockIdx.x * 256 + t;
  if (t < 16) lcnt[t] = 0;
  __syncthreads();
  unsigned pack = sel_pack[tok];
  int eid[KSEL];
  #pragma unroll
  for (int k = 0; k < KSEL; k++) {
    eid[k] = (pack >> (4 * k)) & 15;
    atomicAdd(&lcnt[eid[k]], 1);
  }
  __syncthreads();
  if (t < 16) {
    lbase[t] = atomicAdd(&counts[t * 16], lcnt[t]);
    lcur[t] = 0;
  }
  __syncthreads();
  #pragma unroll
  for (int k = 0; k < KSEL; k++) {
    int e = eid[k];
    int slot = lbase[e] + atomicAdd(&lcur[e], 1);
    tokk[e * TOK_N + slot] = tok * 8 + k;
    affl[e * TOK_N + slot] = aff6[(size_t)tok * KSEL + k];
  }
}

// ---------------- build compact tile list + per-expert prefix base, parallel ----------
// tiles[slot] = e | (mtile << 8); pbase[e] = exclusive prefix of raw counts (scores
// rows are packed per-expert in list order). All LDS-indexed (no scratch, rule #20).
__global__ void tilelist_k(const int* __restrict__ counts, int* __restrict__ tiles,
                           int* __restrict__ ntiles, int* __restrict__ pbase) {
  __shared__ int tc[16], pb[16];
  int t = threadIdx.x;   // 64 threads
  if (t < 16) tc[t] = (counts[t * 16] + 127) >> 7;
  __syncthreads();
  if (t == 0) {
    int s = 0;
    for (int e = 0; e < 16; e++) { pb[e] = s; s += tc[e]; }
    *ntiles = s;
    int s2 = 0;
    for (int e = 0; e < 16; e++) { pbase[e] = s2; s2 += counts[e * 16]; }
  }
  __syncthreads();
  if (t < 16) {
    int b = pb[t], n = tc[t];
    for (int i = 0; i < n; i++) tiles[b + i] = t | (i << 8);
  }
}

// ---------------- grouped GEMM: R22 core + per-XCD contiguous slot chunks ------------
// Core identical to R22 (best, 411us): 128x128xBK=64, 8 waves (2Mx4N, 64x32/wave),
// LDS 2x32KB dbuf, XOR swizzle (0 conflicts), counted-vmcnt schedule (VWAIT4).
// NEW (R23): remap p -> XCD-chunked slots. x=p&7 (round-robin XCD), XCD x owns the
// CONTIGUOUS slot range [x*50, x*50+50), y-innermost within a slot. Co-resident per
// XCD: ~16 contiguous expert-major slots = 1-2 experts' B panels (1-2 MB) -> B stays
// L2-RESIDENT (R22: ~16 experts' panels >> 4MB L2 -> all B reads streamed from L3 at
// its ~4-5 TB/s ceiling — the cross-round invariant wall: equal pass durations at
// equal total K-steps across occupancy 1.7-3.4 w/SIMD, depth 1-3, tile 128-256).
// A-tile y-sibling L2 sharing (R18 win) preserved; block count per XCD exactly equal.
// PASS 2: A = Xbf gathered by token; B = keysT; AK=1024; NY=4;
//         epilogue aff*silu -> bf16 scores, contiguous list-order rows.
// PASS 3: A = scores (contiguous, no gather); B = valuesT; AK=512; NY=8;
//         epilogue: f32 atomicAdd scatter into out[tok][1024].
template<int AK, int PASS, int NY>
__global__ __launch_bounds__(512, 2) void moe_gemm_k(
    const u16* __restrict__ Abase, const u16* __restrict__ Bbase,
    const int* __restrict__ counts, const int* __restrict__ tokk,
    const float* __restrict__ affl, const int* __restrict__ tiles,
    const int* __restrict__ ntiles, const int* __restrict__ pbase,
    u16* __restrict__ scores_out, float* __restrict__ out) {
  int p = blockIdx.x;
  int xcd = p & 7;
  int i = p >> 3;                       // [0, 50*NY)
  int slot = xcd * (MAXTILES / 8) + i / NY;
  int y = i % NY;
  if (slot >= *ntiles) return;
  int desc = tiles[slot];
  int e = desc & 15;
  int m0 = (desc >> 8) << 7;
  int cnt = counts[e * 16];
  int pbe = pbase[e];
  int n0 = y * 128;
  int t = threadIdx.x;
  int lane = t & 63, w = t >> 6;   // 8 waves
  int wr = w >> 2, wc = w & 3;     // 2x4 waves, each 64x32

  __shared__ u16 Al[2][128][64];   // double-buffered; linear (global_load_lds dest)
  __shared__ u16 Bl[2][128][64];

  const int* tl = tokk + e * TOK_N + m0;
  const float* al = affl + e * TOK_N + m0;
  const u16* Bp = Bbase + (size_t)e * 524288;

  f32x4 acc[4][2];
  #pragma unroll
  for (int m = 0; m < 4; m++)
    #pragma unroll
    for (int n = 0; n < 2; n++)
      acc[m][n] = (f32x4){0.f, 0.f, 0.f, 0.f};

  // staging geometry: wave w stages A+B rows [w*16, w*16+16), 8 rows per gload
  // (lane -> row = base + (lane>>3), chunk j = lane&7; row&7 == lane>>3).
  // Source chunk pre-swizzled j ^ (row&7) (rule #21: linear dest, swizzled src).
  int jj = lane & 7, rl = lane >> 3;
  const u16* ag[2]; const u16* bg[2];
  #pragma unroll
  for (int r = 0; r < 2; r++) {
    int row = w * 16 + r * 8 + rl;
    int lr = (m0 + row < cnt) ? row : 0;   // clamp to a valid row (masked at epilogue)
    int ar;
    if (PASS == 2) {
      int tk = tl[lr];
      ar = tk >> 3;                        // gather X row by token
    } else {
      ar = pbe + m0 + lr;                  // contiguous list-order scores row
    }
    int cs = (jj ^ (row & 7)) * 8;         // swizzled source element offset
    ag[r] = Abase + (size_t)ar * AK + cs;
    bg[r] = Bp + (size_t)(n0 + row) * AK + cs;
  }

#define STAGE(B, K0)                                             \
  _Pragma("unroll")                                              \
  for (int r = 0; r < 2; r++) {                                  \
    gload_lds16(ag[r] + (K0), &Al[B][w * 16 + r * 8][0]);        \
    gload_lds16(bg[r] + (K0), &Bl[B][w * 16 + r * 8][0]);        \
  }

#define COMPUTE(B)                                                         \
  _Pragma("unroll")                                                        \
  for (int kk = 0; kk < 2; kk++) {                                         \
    int lc = kk * 4 + (lane >> 4);                                         \
    short8 af[4], bf[2];                                                   \
    _Pragma("unroll")                                                      \
    for (int m = 0; m < 4; m++) {                                          \
      int row = wr * 64 + m * 16 + (lane & 15);                            \
      af[m] = *(const short8*)&Al[B][row][(lc ^ (row & 7)) * 8];           \
    }                                                                      \
    _Pragma("unroll")                                                      \
    for (int n = 0; n < 2; n++) {                                          \
      int row = wc * 32 + n * 16 + (lane & 15);                            \
      bf[n] = *(const short8*)&Bl[B][row][(lc ^ (row & 7)) * 8];           \
    }                                                                      \
    _Pragma("unroll")                                                      \
    for (int m = 0; m < 4; m++)                                            \
      _Pragma("unroll")                                                    \
      for (int n = 0; n < 2; n++)                                          \
        acc[m][n] = __builtin_amdgcn_mfma_f32_16x16x32_bf16(af[m], bf[n],  \
                                                            acc[m][n], 0, 0, 0); \
  }

#define VWAIT4 asm volatile("s_waitcnt vmcnt(4)" ::: "memory")
#define VWAIT0 asm volatile("s_waitcnt vmcnt(0)" ::: "memory")
#define BARR  __builtin_amdgcn_s_barrier()
#define PIN   __builtin_amdgcn_sched_barrier(0)

  constexpr int NIT = AK / 64;   // 16 (pass2) / 8 (pass3) -- even, >= 4
  STAGE(0, 0)                    // 4 loads in flight (buf0)
  #pragma unroll 1
  for (int it = 0; it < NIT - 2; it += 2) {
    STAGE(1, (it + 1) * 64)      // +4 -> 8 in flight
    VWAIT4; BARR; PIN;           // buf0 done everywhere; buf1 loads still flying
    COMPUTE(0)
    BARR; PIN;                   // all waves done reading buf0 -> safe to overwrite
    STAGE(0, (it + 2) * 64)
    VWAIT4; BARR; PIN;           // buf1 done; buf0-next still flying
    COMPUTE(1)
    BARR; PIN;
  }
  // peeled tail: it = NIT-2
  STAGE(1, (NIT - 1) * 64)
  VWAIT4; BARR; PIN;
  COMPUTE(0)
  BARR; PIN;
  VWAIT0; BARR; PIN;             // drain buf1's loads
  COMPUTE(1)

#undef STAGE
#undef COMPUTE
#undef VWAIT4
#undef VWAIT0
#undef BARR
#undef PIN

  int cbase = n0 + wc * 32 + (lane & 15);
  #pragma unroll
  for (int m = 0; m < 4; m++) {
    int rbase = wr * 64 + m * 16 + ((lane >> 4) << 2);   // C/D: col=lane&15, row=(lane>>4)*4+q
    #pragma unroll
    for (int q = 0; q < 4; q++) {
      int row = rbase + q;
      if (m0 + row >= cnt) continue;
      if (PASS == 2) {
        float aff = al[row];
        size_t base = (size_t)(pbe + m0 + row) * FEXP;   // contiguous list-order row
        #pragma unroll
        for (int n = 0; n < 2; n++) {
          float v = acc[m][n][q];
          float s = aff * v / (1.f + expf(-v));   // aff * silu(v)
          scores_out[base + cbase + n * 16] = f2bf(s);
        }
      } else {
        int tk = tl[row];
        size_t base = (size_t)(tk >> 3) * DMODEL;
        #pragma unroll
        for (int n = 0; n < 2; n++)
          atomicAdd(&out[base + cbase + n * 16], acc[m][n][q]);
      }
    }
  }
}

extern "C" void kernel_launch(void* const* d_in, const int* in_sizes, int n_in,
                              void* d_out, int out_size, void* d_ws, size_t ws_size,
                              hipStream_t stream) {
  (void)in_sizes; (void)n_in; (void)out_size; (void)ws_size;
  const float* token_stream    = (const float*)d_in[0];
  const float* selection_input = (const float*)d_in[1];
  const float* keys_w          = (const float*)d_in[2];
  const float* values_w        = (const float*)d_in[3];
  const float* expert_sel      = (const float*)d_in[4];
  const float* bias_ffn        = (const float*)d_in[5];

  float* out     = (float*)d_out;                       // [8192][1024] f32
  float* out_sel = out + (size_t)TOK_N * DMODEL;        // [8192][6] as float

  char* ws = (char*)d_ws;
  u16*      Xbf      = (u16*)(ws + 0);                  // 16 MB
  u16*      keysT    = (u16*)(ws + 16777216);           // 16 MB  [e][512][1024]
  u16*      valuesT  = (u16*)(ws + 33554432);           // 16 MB  [e][1024][512]
  u16*      scoresbf = (u16*)(ws + 50331648);           // 48 MB  [49152 list-order][512]
  int*      counts   = (int*)(ws + 100663296);          // 1 KB (padded, e -> counts[e*16])
  int*      tokk     = (int*)(ws + 100664320);          // 512 KB
  float*    affl     = (float*)(ws + 101188608);        // 512 KB
  unsigned* sel_pack = (unsigned*)(ws + 101712896);     // 32 KB
  float*    aff6     = (float*)(ws + 101745664);        // 192 KB
  int*      tiles    = (int*)(ws + 101942272);          // 4 KB
  int*      ntiles   = (int*)(ws + 101946368);          // 4 B
  int*      pbase    = (int*)(ws + 101946432);          // 64 B

  hipMemsetAsync(out, 0, (size_t)TOK_N * DMODEL * sizeof(float), stream);
  hipMemsetAsync(counts, 0, 1024, stream);

  cast_bf16_k<<<4096, 256, 0, stream>>>(token_stream, Xbf, TOK_N * DMODEL / 8);
  transpose_cast_k<<<dim3(16, 32, 16), dim3(32, 8), 0, stream>>>(keys_w, keysT, 1024, 512);
  transpose_cast_k<<<dim3(32, 16, 16), dim3(32, 8), 0, stream>>>(values_w, valuesT, 512, 1024);

  routing_k<<<TOK_N, 256, 0, stream>>>(selection_input, expert_sel, bias_ffn,
                                       out_sel, sel_pack, aff6);
  scatter_k<<<TOK_N / 256, 256, 0, stream>>>(sel_pack, aff6, counts, tokk, affl);
  tilelist_k<<<1, 64, 0, stream>>>(counts, tiles, ntiles, pbase);

  // scores = aff * silu(X @ K[e]):  M<=49152, N=512, K=1024
  moe_gemm_k<1024, 2, 4><<<MAXTILES * 4, 512, 0, stream>>>(Xbf, keysT, counts, tokk, affl,
                                                           tiles, ntiles, pbase,
                                                           scoresbf, nullptr);
  // out += scores @ V[e]:          M<=49152, N=1024, K=512
  moe_gemm_k<512, 3, 8><<<MAXTILES * 8, 512, 0, stream>>>(scoresbf, valuesT, counts, tokk, affl,
                                                          tiles, ntiles, pbase,
                                                          nullptr, out);
}